// Round 7
// baseline (15640.463 us; speedup 1.0000x reference)
//
#include <hip/hip_runtime.h>
#include <hip/hip_bf16.h>

// LSNN adaptive-LIF scan, T=1000, B=64, N_in=256, N_h=512, fp32.
//
// BITWISE CONSTRAINT (rounds 2-5): harness compares binary spikes exactly;
// flips cascade. The recurrent term for column n MUST be one serial
// ascending-index __fadd_rn chain over active neurons. No partial sums.
// Pad rows (+0.0 from zeroed row 512) are bitwise neutral. absmax 0 across
// all passing rounds.
//
// Round 14: r7-r13 triangulation: latency pipelining (r8/r9/r10), machine-
// level 32-deep asm (r12), and CU-spreading (r11/r13) ALL leave step time
// at 5800-6400 cy. Surviving model: per-vmem-INSTRUCTION cost (~4-8 cy
// TA/TCP occupancy per scalar wave64 gather load); per-CU fill-BW is NOT
// the wall (GEMM kernels pull ~200 B/cy/CU from L2 with dwordx4). Fix:
// vectorize the gather -- stage active rows into LDS cooperatively with
// float4 loads (4x fewer vmem instrs, 1KB/wave-instr coalesced), then each
// thread chains its column from LDS (ds_read_b32, conflict-free).
// KT=12 rows/tile (24KB), 2 LDS buffers (48KB total, under every static
// limit), register-staged issue 2 tiles ahead (2x float4[3] sets, 24 VGPR)
// so L2 latency hides under consume+write of earlier tiles. Serial
// ascending chain per column preserved exactly (tiles consumed in list
// order; pads stage the zeroed row -> +0.0). Topology = r7 (64 WGs x 512
// thr, no cross-WG protocol).

#define TT   1000
#define BB   64
#define NIN  256
#define NH   512
#define KT   12                          // rows per staged tile (KT*128 % 512 == 0)
#define LPAD 64                          // list pad region (staging reads < cnt+KT)
#define PADOFF (NH * 2048)               // byte offset of zeroed row 512 of wT

__device__ constexpr float KV = (float)(0.001 * 100.0);            // DT*TAU_MEM_INV
__device__ constexpr float KI = (float)(0.001 * 200.0);            // DT*TAU_SYN_INV
__device__ constexpr float KB = (float)(0.001 * (1.0 / 800.0));    // DT*TAU_ADAPT_INV
__device__ constexpr float KJ = (float)((1.0 / 800.0) * 1.8);      // TAU_ADAPT_INV*BETA

// ---------------- transpose w_rec (512x512): wT[j][n] = w_rec[n][j] ----------
__global__ void transp512(const float* __restrict__ in, float* __restrict__ ot) {
    __shared__ float tile[32][33];
    const int tx = threadIdx.x;            // 0..31
    const int ty = threadIdx.y;            // 0..7
    const int jcol = blockIdx.x * 32 + tx;
    const int row0 = blockIdx.y * 32;
    for (int r = ty; r < 32; r += 8)
        tile[r][tx] = in[(size_t)(row0 + r) * NH + jcol];
    __syncthreads();
    const int ncol = blockIdx.y * 32 + tx;
    const int jrow0 = blockIdx.x * 32;
    for (int r = ty; r < 32; r += 8)
        ot[(size_t)(jrow0 + r) * NH + ncol] = tile[tx][r];
}

// zero row 512 of wT (padding target for unconditional staging tiles)
__global__ void zrow(float* __restrict__ wT) {
    wT[(size_t)NH * NH + threadIdx.x] = 0.0f;
}

// ---------------- fp32 GEMM: F[m][n] = sum_k X[m][k] * W[n][k] ---------------
// UNCHANGED from round 2 (bitwise-verified against the np reference).
__global__ __launch_bounds__(256)
void gemm_ff(const float* __restrict__ X, const float* __restrict__ W,
             float* __restrict__ F, int M) {
    const int bx = blockIdx.x;   // n-tile: 0..3
    const int by = blockIdx.y;   // m-tile
    const int tid = threadIdx.x;

    __shared__ float As[32][128];
    __shared__ float Bs[32][128];

    const int tn0 = (tid & 15) * 8;
    const int tm0 = (tid >> 4) * 8;
    float acc[8][8] = {};

    const int am = tid >> 1;
    const int aq = (tid & 1) * 4;

    const float* Xb = X + (size_t)(by * 128 + am) * NIN;
    const float* Wb = W + (size_t)(bx * 128 + am) * NIN;

    for (int k0 = 0; k0 < NIN; k0 += 32) {
        __syncthreads();
#pragma unroll
        for (int i2 = 0; i2 < 4; ++i2) {
            const int q = aq + i2;
            float4 xa = *reinterpret_cast<const float4*>(Xb + k0 + q * 4);
            As[q * 4 + 0][am] = xa.x; As[q * 4 + 1][am] = xa.y;
            As[q * 4 + 2][am] = xa.z; As[q * 4 + 3][am] = xa.w;
            float4 wa = *reinterpret_cast<const float4*>(Wb + k0 + q * 4);
            Bs[q * 4 + 0][am] = wa.x; Bs[q * 4 + 1][am] = wa.y;
            Bs[q * 4 + 2][am] = wa.z; Bs[q * 4 + 3][am] = wa.w;
        }
        __syncthreads();
#pragma unroll 8
        for (int kk = 0; kk < 32; ++kk) {
            float4 a0 = *reinterpret_cast<const float4*>(&As[kk][tm0]);
            float4 a1 = *reinterpret_cast<const float4*>(&As[kk][tm0 + 4]);
            float4 b0 = *reinterpret_cast<const float4*>(&Bs[kk][tn0]);
            float4 b1 = *reinterpret_cast<const float4*>(&Bs[kk][tn0 + 4]);
            const float av[8] = {a0.x, a0.y, a0.z, a0.w, a1.x, a1.y, a1.z, a1.w};
            const float bv[8] = {b0.x, b0.y, b0.z, b0.w, b1.x, b1.y, b1.z, b1.w};
#pragma unroll
            for (int i = 0; i < 8; ++i)
#pragma unroll
                for (int j = 0; j < 8; ++j)
                    acc[i][j] += av[i] * bv[j];
        }
    }

    float* Fo = F + (size_t)(by * 128 + tm0) * NH + bx * 128 + tn0;
#pragma unroll
    for (int i = 0; i < 8; ++i) {
        *reinterpret_cast<float4*>(Fo + (size_t)i * NH) =
            make_float4(acc[i][0], acc[i][1], acc[i][2], acc[i][3]);
        *reinterpret_cast<float4*>(Fo + (size_t)i * NH + 4) =
            make_float4(acc[i][4], acc[i][5], acc[i][6], acc[i][7]);
    }
}

// ---------------- staged-gather helpers --------------------------------------
// Tile = KT rows x 512 cols x 4B = KT*2KB. 512 threads stage 3 float4 chunks
// each (chunk g = c*512+tid: row = g>>7 is wave-uniform, addresses are 64
// consecutive 16B per wave -> perfectly coalesced dwordx4).
__device__ __forceinline__ void stage_issue(float4 (&r)[3], const int* lp,
                                            int kt, const char* wb, int tid) {
#pragma unroll
    for (int c = 0; c < 3; ++c) {
        const int g = c * 512 + tid;
        const int off = lp[kt + (g >> 7)];          // wave-uniform broadcast
        r[c] = *reinterpret_cast<const float4*>(
            wb + (unsigned)off + (unsigned)((g & 127) << 4));
    }
}
__device__ __forceinline__ void stage_write(const float4 (&r)[3], float* dst,
                                            int tid) {
#pragma unroll
    for (int c = 0; c < 3; ++c) {
        const int g = c * 512 + tid;
        *reinterpret_cast<float4*>(dst + (size_t)g * 4) = r[c];   // ds_write_b128
    }
}
// One ascending-index serial chain link per row (bitwise == BLAS).
__device__ __forceinline__ void consume(const float* buf, int nn, float& rec) {
#pragma unroll
    for (int k = 0; k < KT; ++k) rec = __fadd_rn(rec, buf[k * NH + nn]);
}

// ---------------- scan kernel: one WG (512 thr) per batch element -----------
// st layout: [z | v | i | b], each BB*NH floats.
__global__ __launch_bounds__(512, 1)
void lsnn_scan(const float* __restrict__ F, const float* __restrict__ wT,
               const float* __restrict__ z0, const float* __restrict__ v0,
               const float* __restrict__ i0, const float* __restrict__ b0,
               float* __restrict__ out, float* __restrict__ st,
               int t0, int Tc, int first, int last) {
    const int n    = threadIdx.x;        // neuron / column 0..511
    const int b    = blockIdx.x;         // batch
    const int lane = n & 63;
    const int wv   = n >> 6;             // wave 0..7
    const size_t bn = (size_t)b * NH + n;

    __shared__ __align__(16) float sbuf[2][KT * NH];   // 48 KB staging
    __shared__ __align__(16) int list_[NH + LPAD];     // row byte offsets + pad
    __shared__ int cnts2[8];

    float v, cur, bb, zprev;
    if (first) {
        zprev = z0[bn]; v = v0[bn]; cur = i0[bn]; bb = b0[bn];
    } else {
        zprev = st[0 * BB * NH + bn];
        v     = st[1 * BB * NH + bn];
        cur   = st[2 * BB * NH + bn];
        bb    = st[3 * BB * NH + bn];
    }

    // ---- initial list build, ascending neuron order ------------------------
    int cnt;
    {
        const unsigned long long m = __ballot(zprev > 0.0f);
        if (lane == 0) cnts2[wv] = __popcll(m);
        __syncthreads();
        int base = 0, tot = 0;
        for (int q = 0; q < 8; ++q) {
            const int c0 = cnts2[q];
            if (q < wv) base += c0;
            tot += c0;
        }
        if (zprev > 0.0f)
            list_[base + __popcll(m & ((1ull << lane) - 1ull))] = n << 11;
        if (n < LPAD) list_[tot + n] = PADOFF;   // pad region
        __syncthreads();
        cnt = tot;
    }

    const char*  wb = reinterpret_cast<const char*>(wT);   // uniform base (SGPR)
    const float* Fp = F + (size_t)b * NH + n;
    float* op = out + ((size_t)t0 * BB + b) * NH + n;

    for (int t = 0; t < Tc; ++t) {
        // ---- t.1: elementwise update, ballot, publish next counts ----------
        const float v_dec = __fadd_rn(v, __fmul_rn(KV, __fadd_rn(__fsub_rn(0.0f, v), cur)));
        const float i_dec = __fsub_rn(cur, __fmul_rn(KI, cur));
        const float b_dec = __fadd_rn(bb, __fmul_rn(KB, __fsub_rn(1.0f, bb)));
        const float zn = (__fsub_rn(v_dec, b_dec) > 0.0f) ? 1.0f : 0.0f;
        v  = (zn > 0.0f) ? 0.0f : v_dec;
        bb = __fadd_rn(b_dec, __fmul_rn(zn, KJ));
        const unsigned long long mm = __ballot(zn > 0.0f);
        if (lane == 0) cnts2[wv] = __popcll(mm);

        // ---- t.2: out store + F prefetch + staged gather --------------------
        op[0] = zn;
        op += (size_t)BB * NH;
        const float fval = Fp[(size_t)t * BB * NH];   // consumed after gather

        float rec = 0.0f;
        if (cnt > 0) {
            const int nt = (cnt + KT - 1) / KT;
            float4 rgA[3], rgB[3];
            // prologue: tiles 0,1 in flight; tile0 -> buf0
            stage_issue(rgA, list_, 0, wb, n);
            if (nt > 1) stage_issue(rgB, list_, KT, wb, n);
            __builtin_amdgcn_sched_barrier(0);
            stage_write(rgA, &sbuf[0][0], n);
            __syncthreads();                          // S0: buf0 ready
            for (int tt = 0; tt < nt; ++tt) {
                const int cb = tt & 1;
                // issue tile tt+2 into the reg set freed last iteration
                if (tt + 2 < nt) {
                    if ((tt & 1) == 0) stage_issue(rgA, list_, (tt + 2) * KT, wb, n);
                    else               stage_issue(rgB, list_, (tt + 2) * KT, wb, n);
                    __builtin_amdgcn_sched_barrier(0);
                }
                consume(&sbuf[cb][0], n, rec);        // serial chain, tile tt
                __builtin_amdgcn_sched_barrier(0);
                // write tile tt+1 (issued 2 iterations ago; loads landed)
                if (tt + 1 < nt) {
                    if ((tt & 1) == 0) stage_write(rgB, &sbuf[cb ^ 1][0], n);
                    else               stage_write(rgA, &sbuf[cb ^ 1][0], n);
                }
                __syncthreads();                      // buf tt+1 ready; tt drained
            }
        }
        cur = __fadd_rn(__fadd_rn(i_dec, fval), rec);
        zprev = zn;

        __syncthreads();   // B1: cnts2 visible; list_ free for rebuild

        // ---- t.3: build next list ------------------------------------------
        int base = 0, tot = 0;
        for (int q = 0; q < 8; ++q) {
            const int c0 = cnts2[q];
            if (q < wv) base += c0;
            tot += c0;
        }
        if (zn > 0.0f)
            list_[base + __popcll(mm & ((1ull << lane) - 1ull))] = n << 11;
        if (n < LPAD) list_[tot + n] = PADOFF;
        __syncthreads();   // B2: list ready

        cnt = tot;
    }

    st[0 * BB * NH + bn] = zprev;
    st[1 * BB * NH + bn] = v;
    st[2 * BB * NH + bn] = cur;
    st[3 * BB * NH + bn] = bb;
    if (last) {
        float* tail = out + (size_t)TT * BB * NH;
        tail[0 * BB * NH + bn] = zprev;  // zT
        tail[1 * BB * NH + bn] = v;      // vT
        tail[2 * BB * NH + bn] = cur;    // iT
        tail[3 * BB * NH + bn] = bb;     // bT
    }
}

// ---------------------------------------------------------------------------
extern "C" void kernel_launch(void* const* d_in, const int* in_sizes, int n_in,
                              void* d_out, int out_size, void* d_ws, size_t ws_size,
                              hipStream_t stream) {
    const float* X     = (const float*)d_in[0];
    const float* z0    = (const float*)d_in[1];
    const float* v0    = (const float*)d_in[2];
    const float* i0    = (const float*)d_in[3];
    const float* b0    = (const float*)d_in[4];
    const float* w_in  = (const float*)d_in[5];
    const float* w_rec = (const float*)d_in[6];
    float* out = (float*)d_out;

    char* ws = (char*)d_ws;
    float* wT = (float*)ws;                                    // 1 MB + zero row
    const size_t wT_bytes = ((size_t)NH * NH + NH) * 4 + 2048;
    float* st = (float*)(ws + wT_bytes);                       // 512 KB
    char*  fbase = ws + wT_bytes + (512u << 10);

    const long long per = (long long)BB * NH * 4;              // bytes/step of F
    long long avail = (long long)ws_size - (long long)(wT_bytes + (512u << 10));
    int Tc;
    if (avail >= 2 * per * TT) {
        Tc = TT;
    } else {
        Tc = (int)(avail / (2 * per));
        if (Tc > TT) Tc = TT;
        Tc &= ~1;
        if (Tc < 2) Tc = 2;
    }
    const size_t fbytes = (size_t)Tc * per;
    float* Fb[2] = { (float*)fbase, (float*)(fbase + fbytes) };

    transp512<<<dim3(16, 16), dim3(32, 8), 0, stream>>>(w_rec, wT);
    zrow<<<1, NH, 0, stream>>>(wT);

    int t0 = 0, buf = 0;
    bool firstc = true;
    while (t0 < TT) {
        const int Tcur = (Tc < TT - t0) ? Tc : (TT - t0);
        const int Mc = Tcur * BB;
        gemm_ff<<<dim3(4, Mc / 128), 256, 0, stream>>>(
            X + (size_t)t0 * BB * NIN, w_in, Fb[buf], Mc);
        lsnn_scan<<<dim3(BB), dim3(512), 0, stream>>>(
            Fb[buf], wT, z0, v0, i0, b0, out, st,
            t0, Tcur, firstc ? 1 : 0, (t0 + Tcur >= TT) ? 1 : 0);
        firstc = false;
        buf ^= 1;
        t0 += Tcur;
    }
}

// Round 9
// 2931.304 us; speedup vs baseline: 5.3357x; 5.3357x over previous
//
#include <hip/hip_runtime.h>
#include <hip/hip_bf16.h>

// LSNN adaptive-LIF scan, T=1000, B=64, N_in=256, N_h=512, fp32.
//
// BITWISE CONSTRAINT (rounds 2-5): harness compares binary spikes exactly;
// flips cascade. The recurrent term for column n MUST be one serial
// ascending-index __fadd_rn chain over active neurons. No partial sums.
// Pad rows (+0.0 from zeroed row 512) are bitwise neutral. absmax 0 across
// all passing rounds.
//
// Round 16 = round 15 RESUBMIT (bench infra failed: "container failed
// twice", no kernel verdict). Probe unchanged:
// r7-r14 full triangulation. Invariant across r7 (compiler, 8 waves/CU),
// r12 (asm 32-deep, 8 waves/CU), r13 (asm, 4 waves/CU, half per-CU
// bytes+instrs): ~5800-6100 cy/step. Per-CU bytes, per-CU instr rate,
// in-flight depth, latency distance: all experimentally refuted.
// Surviving invariant: PER-WAVE return rate ~20 B/cy (64KB/wave/step ->
// ~3200cy floor + overhead) == effective per-wave miss concurrency ~16,
// BELOW r12's vmcnt depth of 32 -> the cap sits in the L1/TCP miss path,
// not the vmcnt queue. Per-wave data is fixed by the bitwise serial-chain
// constraint, so the only lever is the per-wave return rate itself.
// SINGLE VARIABLE: `sc0` on the 48 gather loads -- gfx950 L1-bypass
// (fetch from coherent point, no L1 allocation). wT is 1MB vs 32KB L1:
// hit rate ~0, bypass is loss-free; if the ~16-deep cap is L1 miss
// handling, rate rises. If neutral: cap is the wave's TCP return queue ->
// mechanism-level roofline; next round reverts to r7 scaffold and trims.
// Also LPAD 64->96 (asm reads offsets to cnt+78).

#define TT   1000
#define BB   64
#define NIN  256
#define NH   512
#define LPAD 96                          // asm reads offsets up to cnt+78
#define PADOFF (NH * 2048)               // byte offset of zeroed row 512 of wT

__device__ constexpr float KV = (float)(0.001 * 100.0);            // DT*TAU_MEM_INV
__device__ constexpr float KI = (float)(0.001 * 200.0);            // DT*TAU_SYN_INV
__device__ constexpr float KB = (float)(0.001 * (1.0 / 800.0));    // DT*TAU_ADAPT_INV
__device__ constexpr float KJ = (float)((1.0 / 800.0) * 1.8);      // TAU_ADAPT_INV*BETA

// ---------------- transpose w_rec (512x512): wT[j][n] = w_rec[n][j] ----------
__global__ void transp512(const float* __restrict__ in, float* __restrict__ ot) {
    __shared__ float tile[32][33];
    const int tx = threadIdx.x;            // 0..31
    const int ty = threadIdx.y;            // 0..7
    const int jcol = blockIdx.x * 32 + tx;
    const int row0 = blockIdx.y * 32;
    for (int r = ty; r < 32; r += 8)
        tile[r][tx] = in[(size_t)(row0 + r) * NH + jcol];
    __syncthreads();
    const int ncol = blockIdx.y * 32 + tx;
    const int jrow0 = blockIdx.x * 32;
    for (int r = ty; r < 32; r += 8)
        ot[(size_t)(jrow0 + r) * NH + ncol] = tile[tx][r];
}

// zero row 512 of wT (padding target for unconditional gather tiles)
__global__ void zrow(float* __restrict__ wT) {
    wT[(size_t)NH * NH + threadIdx.x] = 0.0f;
}

// ---------------- fp32 GEMM: F[m][n] = sum_k X[m][k] * W[n][k] ---------------
// UNCHANGED from round 2 (bitwise-verified against the np reference).
__global__ __launch_bounds__(256)
void gemm_ff(const float* __restrict__ X, const float* __restrict__ W,
             float* __restrict__ F, int M) {
    const int bx = blockIdx.x;   // n-tile: 0..3
    const int by = blockIdx.y;   // m-tile
    const int tid = threadIdx.x;

    __shared__ float As[32][128];
    __shared__ float Bs[32][128];

    const int tn0 = (tid & 15) * 8;
    const int tm0 = (tid >> 4) * 8;
    float acc[8][8] = {};

    const int am = tid >> 1;
    const int aq = (tid & 1) * 4;

    const float* Xb = X + (size_t)(by * 128 + am) * NIN;
    const float* Wb = W + (size_t)(bx * 128 + am) * NIN;

    for (int k0 = 0; k0 < NIN; k0 += 32) {
        __syncthreads();
#pragma unroll
        for (int i2 = 0; i2 < 4; ++i2) {
            const int q = aq + i2;
            float4 xa = *reinterpret_cast<const float4*>(Xb + k0 + q * 4);
            As[q * 4 + 0][am] = xa.x; As[q * 4 + 1][am] = xa.y;
            As[q * 4 + 2][am] = xa.z; As[q * 4 + 3][am] = xa.w;
            float4 wa = *reinterpret_cast<const float4*>(Wb + k0 + q * 4);
            Bs[q * 4 + 0][am] = wa.x; Bs[q * 4 + 1][am] = wa.y;
            Bs[q * 4 + 2][am] = wa.z; Bs[q * 4 + 3][am] = wa.w;
        }
        __syncthreads();
#pragma unroll 8
        for (int kk = 0; kk < 32; ++kk) {
            float4 a0 = *reinterpret_cast<const float4*>(&As[kk][tm0]);
            float4 a1 = *reinterpret_cast<const float4*>(&As[kk][tm0 + 4]);
            float4 b0 = *reinterpret_cast<const float4*>(&Bs[kk][tn0]);
            float4 b1 = *reinterpret_cast<const float4*>(&Bs[kk][tn0 + 4]);
            const float av[8] = {a0.x, a0.y, a0.z, a0.w, a1.x, a1.y, a1.z, a1.w};
            const float bv[8] = {b0.x, b0.y, b0.z, b0.w, b1.x, b1.y, b1.z, b1.w};
#pragma unroll
            for (int i = 0; i < 8; ++i)
#pragma unroll
                for (int j = 0; j < 8; ++j)
                    acc[i][j] += av[i] * bv[j];
        }
    }

    float* Fo = F + (size_t)(by * 128 + tm0) * NH + bx * 128 + tn0;
#pragma unroll
    for (int i = 0; i < 8; ++i) {
        *reinterpret_cast<float4*>(Fo + (size_t)i * NH) =
            make_float4(acc[i][0], acc[i][1], acc[i][2], acc[i][3]);
        *reinterpret_cast<float4*>(Fo + (size_t)i * NH + 4) =
            make_float4(acc[i][4], acc[i][5], acc[i][6], acc[i][7]);
    }
}

// ---------------- asm gather building blocks ---------------------------------
// GLD: compute address (row byte offset + column byte offset) and issue load
// with sc0 (L1 bypass: fetch from coherent point, no L1 allocation).
#define GLD(o, d) \
    "v_add_u32 v82, %[n4], " o "\n\t" \
    "global_load_dword " d ", v82, %[wb] sc0\n\t"
// ADDF: one link of the ascending serial chain (bitwise-mandated order).
#define ADDF(s) "v_add_f32 %[rec], %[rec], " s "\n\t"

// ---------------- scan kernel: one WG (512 thr) per batch element -----------
// st layout: [z | v | i | b], each BB*NH floats.
__global__ __launch_bounds__(512, 1)
void lsnn_scan(const float* __restrict__ F, const float* __restrict__ wT,
               const float* __restrict__ z0, const float* __restrict__ v0,
               const float* __restrict__ i0, const float* __restrict__ b0,
               float* __restrict__ out, float* __restrict__ st,
               int t0, int Tc, int first, int last) {
    const int n    = threadIdx.x;        // neuron / column 0..511
    const int b    = blockIdx.x;         // batch
    const int lane = n & 63;
    const int wv   = n >> 6;             // wave 0..7
    const size_t bn = (size_t)b * NH + n;

    __shared__ __align__(16) int lists[2][NH + LPAD];  // row byte offsets + pad
    __shared__ int cnts[2][8];

    float v, cur, bb, zprev;
    if (first) {
        zprev = z0[bn]; v = v0[bn]; cur = i0[bn]; bb = b0[bn];
    } else {
        zprev = st[0 * BB * NH + bn];
        v     = st[1 * BB * NH + bn];
        cur   = st[2 * BB * NH + bn];
        bb    = st[3 * BB * NH + bn];
    }

    // ---- initial list build (buffer 0), ascending neuron order -------------
    int cnt;
    {
        const unsigned long long m = __ballot(zprev > 0.0f);
        if (lane == 0) cnts[0][wv] = __popcll(m);
        __syncthreads();
        int base = 0, tot = 0;
        for (int q = 0; q < 8; ++q) {
            const int c = cnts[0][q];
            if (q < wv) base += c;
            tot += c;
        }
        if (zprev > 0.0f)
            lists[0][base + __popcll(m & ((1ull << lane) - 1ull))] = n << 11;
        if (n < LPAD) lists[0][tot + n] = PADOFF;   // pad region
        __syncthreads();
        cnt = tot;
    }
    int par = 0;

    const char*  wb = reinterpret_cast<const char*>(wT);   // uniform base (SGPR)
    const unsigned n4 = (unsigned)n * 4u;                  // column byte offset
    const float* Fp = F + (size_t)b * NH + n;
    float* op = out + ((size_t)t0 * BB + b) * NH + n;

    for (int t = 0; t < Tc; ++t) {
        // ---- t.1: elementwise update, ballot, publish next counts ----------
        const float v_dec = __fadd_rn(v, __fmul_rn(KV, __fadd_rn(__fsub_rn(0.0f, v), cur)));
        const float i_dec = __fsub_rn(cur, __fmul_rn(KI, cur));
        const float b_dec = __fadd_rn(bb, __fmul_rn(KB, __fsub_rn(1.0f, bb)));
        const float zn = (__fsub_rn(v_dec, b_dec) > 0.0f) ? 1.0f : 0.0f;
        v  = (zn > 0.0f) ? 0.0f : v_dec;
        bb = __fadd_rn(b_dec, __fmul_rn(zn, KJ));
        const unsigned long long mm = __ballot(zn > 0.0f);
        if (lane == 0) cnts[par ^ 1][wv] = __popcll(mm);

        // ---- t.2: F prefetch (hidden under the asm gather) + asm gather ----
        const float fval = Fp[(size_t)t * BB * NH];

        float rec = 0.0f;
        {
            const unsigned lds_off =
                (unsigned)(unsigned long long)(const void*)lists[par];
            // 2-tile (16-elem) software pipeline, all in one asm block:
            //   prologue: offs(0) -> issue tile0 -> A
            //   loop:     offs(k+1,k+2); issue k+1 -> B; vmcnt(16); add A;
            //             issue k+2 -> A; vmcnt(16); add B; rem -= 32
            //   epilogue: vmcnt(0) drain (clobbered regs must be quiescent)
            // Consumes ceil(cnt/32)*32 entries (pads are +0.0, bitwise-safe).
            asm volatile(
                "v_mov_b32 v80, %[lds]\n\t"
                "v_mov_b32 v81, %[cnt]\n\t"
                "ds_read_b128 v[84:87], v80\n\t"
                "ds_read_b128 v[88:91], v80 offset:16\n\t"
                "ds_read_b128 v[92:95], v80 offset:32\n\t"
                "ds_read_b128 v[96:99], v80 offset:48\n\t"
                "v_add_u32 v80, 64, v80\n\t"
                "s_waitcnt lgkmcnt(0)\n\t"
                GLD("v84", "v116") GLD("v85", "v117")
                GLD("v86", "v118") GLD("v87", "v119")
                GLD("v88", "v120") GLD("v89", "v121")
                GLD("v90", "v122") GLD("v91", "v123")
                GLD("v92", "v124") GLD("v93", "v125")
                GLD("v94", "v126") GLD("v95", "v127")
                GLD("v96", "v128") GLD("v97", "v129")
                GLD("v98", "v130") GLD("v99", "v131")
                "Lg%=:\n\t"
                "ds_read_b128 v[84:87], v80\n\t"
                "ds_read_b128 v[88:91], v80 offset:16\n\t"
                "ds_read_b128 v[92:95], v80 offset:32\n\t"
                "ds_read_b128 v[96:99], v80 offset:48\n\t"
                "ds_read_b128 v[100:103], v80 offset:64\n\t"
                "ds_read_b128 v[104:107], v80 offset:80\n\t"
                "ds_read_b128 v[108:111], v80 offset:96\n\t"
                "ds_read_b128 v[112:115], v80 offset:112\n\t"
                "v_add_u32 v80, 128, v80\n\t"
                "s_waitcnt lgkmcnt(4)\n\t"
                GLD("v84", "v132") GLD("v85", "v133")
                GLD("v86", "v134") GLD("v87", "v135")
                GLD("v88", "v136") GLD("v89", "v137")
                GLD("v90", "v138") GLD("v91", "v139")
                GLD("v92", "v140") GLD("v93", "v141")
                GLD("v94", "v142") GLD("v95", "v143")
                GLD("v96", "v144") GLD("v97", "v145")
                GLD("v98", "v146") GLD("v99", "v147")
                "s_waitcnt vmcnt(16)\n\t"
                ADDF("v116") ADDF("v117") ADDF("v118") ADDF("v119")
                ADDF("v120") ADDF("v121") ADDF("v122") ADDF("v123")
                ADDF("v124") ADDF("v125") ADDF("v126") ADDF("v127")
                ADDF("v128") ADDF("v129") ADDF("v130") ADDF("v131")
                "s_waitcnt lgkmcnt(0)\n\t"
                GLD("v100", "v116") GLD("v101", "v117")
                GLD("v102", "v118") GLD("v103", "v119")
                GLD("v104", "v120") GLD("v105", "v121")
                GLD("v106", "v122") GLD("v107", "v123")
                GLD("v108", "v124") GLD("v109", "v125")
                GLD("v110", "v126") GLD("v111", "v127")
                GLD("v112", "v128") GLD("v113", "v129")
                GLD("v114", "v130") GLD("v115", "v131")
                "s_waitcnt vmcnt(16)\n\t"
                ADDF("v132") ADDF("v133") ADDF("v134") ADDF("v135")
                ADDF("v136") ADDF("v137") ADDF("v138") ADDF("v139")
                ADDF("v140") ADDF("v141") ADDF("v142") ADDF("v143")
                ADDF("v144") ADDF("v145") ADDF("v146") ADDF("v147")
                "v_subrev_u32 v81, 32, v81\n\t"
                "v_cmp_lt_i32 vcc, 0, v81\n\t"
                "s_cbranch_vccnz Lg%=\n\t"
                "s_waitcnt vmcnt(0)\n\t"
                : [rec] "+v"(rec)
                : [lds] "v"(lds_off), [cnt] "v"(cnt), [n4] "v"(n4),
                  [wb] "s"(wb)
                : "v80", "v81", "v82",
                  "v84", "v85", "v86", "v87", "v88", "v89", "v90", "v91",
                  "v92", "v93", "v94", "v95", "v96", "v97", "v98", "v99",
                  "v100", "v101", "v102", "v103", "v104", "v105", "v106", "v107",
                  "v108", "v109", "v110", "v111", "v112", "v113", "v114", "v115",
                  "v116", "v117", "v118", "v119", "v120", "v121", "v122", "v123",
                  "v124", "v125", "v126", "v127", "v128", "v129", "v130", "v131",
                  "v132", "v133", "v134", "v135", "v136", "v137", "v138", "v139",
                  "v140", "v141", "v142", "v143", "v144", "v145", "v146", "v147",
                  "vcc", "memory");
        }

        op[0] = zn;
        op += (size_t)BB * NH;
        cur = __fadd_rn(__fadd_rn(i_dec, fval), rec);
        zprev = zn;

        __syncthreads();   // B1: cnts[par^1] published; lists[par] drained

        // ---- t.3: build next list (lists[par^1]) ----------------------------
        int base = 0, tot = 0;
        for (int q = 0; q < 8; ++q) {
            const int c = cnts[par ^ 1][q];
            if (q < wv) base += c;
            tot += c;
        }
        if (zn > 0.0f)
            lists[par ^ 1][base + __popcll(mm & ((1ull << lane) - 1ull))] = n << 11;
        if (n < LPAD) lists[par ^ 1][tot + n] = PADOFF;
        __syncthreads();   // B2: lists[par^1] ready

        par ^= 1;
        cnt = tot;
    }

    st[0 * BB * NH + bn] = zprev;
    st[1 * BB * NH + bn] = v;
    st[2 * BB * NH + bn] = cur;
    st[3 * BB * NH + bn] = bb;
    if (last) {
        float* tail = out + (size_t)TT * BB * NH;
        tail[0 * BB * NH + bn] = zprev;  // zT
        tail[1 * BB * NH + bn] = v;      // vT
        tail[2 * BB * NH + bn] = cur;    // iT
        tail[3 * BB * NH + bn] = bb;     // bT
    }
}

// ---------------------------------------------------------------------------
extern "C" void kernel_launch(void* const* d_in, const int* in_sizes, int n_in,
                              void* d_out, int out_size, void* d_ws, size_t ws_size,
                              hipStream_t stream) {
    const float* X     = (const float*)d_in[0];
    const float* z0    = (const float*)d_in[1];
    const float* v0    = (const float*)d_in[2];
    const float* i0    = (const float*)d_in[3];
    const float* b0    = (const float*)d_in[4];
    const float* w_in  = (const float*)d_in[5];
    const float* w_rec = (const float*)d_in[6];
    float* out = (float*)d_out;

    char* ws = (char*)d_ws;
    float* wT = (float*)ws;                                    // 1 MB + zero row
    const size_t wT_bytes = ((size_t)NH * NH + NH) * 4 + 2048;
    float* st = (float*)(ws + wT_bytes);                       // 512 KB
    char*  fbase = ws + wT_bytes + (512u << 10);

    const long long per = (long long)BB * NH * 4;              // bytes/step of F
    long long avail = (long long)ws_size - (long long)(wT_bytes + (512u << 10));
    int Tc;
    if (avail >= 2 * per * TT) {
        Tc = TT;
    } else {
        Tc = (int)(avail / (2 * per));
        if (Tc > TT) Tc = TT;
        Tc &= ~1;
        if (Tc < 2) Tc = 2;
    }
    const size_t fbytes = (size_t)Tc * per;
    float* Fb[2] = { (float*)fbase, (float*)(fbase + fbytes) };

    transp512<<<dim3(16, 16), dim3(32, 8), 0, stream>>>(w_rec, wT);
    zrow<<<1, NH, 0, stream>>>(wT);

    int t0 = 0, buf = 0;
    bool firstc = true;
    while (t0 < TT) {
        const int Tcur = (Tc < TT - t0) ? Tc : (TT - t0);
        const int Mc = Tcur * BB;
        gemm_ff<<<dim3(4, Mc / 128), 256, 0, stream>>>(
            X + (size_t)t0 * BB * NIN, w_in, Fb[buf], Mc);
        lsnn_scan<<<dim3(BB), dim3(512), 0, stream>>>(
            Fb[buf], wT, z0, v0, i0, b0, out, st,
            t0, Tcur, firstc ? 1 : 0, (t0 + Tcur >= TT) ? 1 : 0);
        firstc = false;
        buf ^= 1;
        t0 += Tcur;
    }
}